// Round 9
// baseline (273.362 us; speedup 1.0000x reference)
//
#include <hip/hip_runtime.h>
#include <math.h>

#define L    1024
#define D    256
#define NCH  3
#define HEADS 32      // B*N
#define EDIM 112
#define BATCH 4

typedef __bf16 bf8_t __attribute__((ext_vector_type(8)));
typedef float  f4_t  __attribute__((ext_vector_type(4)));

typedef __attribute__((address_space(1))) const void GVC;
typedef __attribute__((address_space(3))) void LDSV;

// RNE float->bf16
__device__ inline unsigned short f2bf(float x) {
    unsigned u = __float_as_uint(x);
    u += 0x7FFFu + ((u >> 16) & 1u);
    return (unsigned short)(u >> 16);
}
__device__ inline float bf2f(unsigned short h) {
    return __uint_as_float(((unsigned)h) << 16);
}

// ------- fused prologue: pe_d table + edge + xs + whb (frag-major bf16) ----
__global__ void prep_kernel(const float* __restrict__ edge, const float* __restrict__ xi,
                            const float* __restrict__ Wq, const float* __restrict__ Wk,
                            const float* __restrict__ Wv,
                            float* __restrict__ pe_d, float* __restrict__ eout,
                            float* __restrict__ xsb, unsigned short* __restrict__ whb)
{
    int idx = blockIdx.x * blockDim.x + threadIdx.x;
    if (idx < L * D) {
        int l = idx >> 8, i = idx & (D - 1);
        float expo = (float)(i & ~1) * (1.0f / (float)D);
        float ang = (float)l * __powf(10000.0f, -expo);
        pe_d[idx] = (i & 1) ? cosf(ang) : sinf(ang);
    } else if (idx < L * D + BATCH * L * EDIM) {
        int j = idx - L * D;
        int i = j % EDIM;
        int l = (j / EDIM) % L;
        float expo = (float)(i & ~1) * (1.0f / (float)EDIM);
        float ang = (float)l * __powf(10000.0f, -expo);
        eout[j] = edge[j] + ((i & 1) ? cosf(ang) : sinf(ang));
    } else if (idx < L * D + BATCH * L * EDIM + HEADS * L * NCH) {
        int j = idx - (L * D + BATCH * L * EDIM);
        int c = j % 3;
        int l = (j / 3) & (L - 1);
        float ang = (c == 2) ? (float)l * 0.0021544347f : (float)l;  // 10000^(-2/3)
        float pe = (c == 1) ? cosf(ang) : sinf(ang);
        xsb[j] = xi[j] + pe;
    } else {
        int j = idx - (L * D + BATCH * L * EDIM + HEADS * L * NCH);
        if (j < 3 * 8192) {                       // W -> bf16, fragment-major
            int wsel = j >> 13;
            int t = j & 8191;
            int g = t >> 9, u = (t >> 4) & 31, rr = t & 15;
            const float* W = (wsel == 0) ? Wq : (wsel == 1) ? Wk : Wv;
            const float4* s = reinterpret_cast<const float4*>(&W[(size_t)(g * 16 + rr) * D + u * 8]);
            float4 a = s[0], b = s[1];
            float x[8] = {a.x, a.y, a.z, a.w, b.x, b.y, b.z, b.w};
            union { unsigned short us[8]; float4 f4; } hv;
            #pragma unroll
            for (int q = 0; q < 8; q++) hv.us[q] = f2bf(x[q]);
            *reinterpret_cast<float4*>(&whb[(size_t)wsel * 65536 + g * 4096 + u * 128 + rr * 8]) = hv.f4;
        }
    }
}

// ---------------- QKV projection v9: X in registers, W counted-vmcnt -------
// R8 diagnosis: per-iteration vmcnt(0)-drain + barrier exposed a full memory
// latency x8 iterations (all pipes <22%). v9: each wave converts ITS X
// quarter into 128 VGPR once (frag layout, hi/lo); k-loop stages only the
// L2-hot W tiles 4-deep with counted vmcnt(4) + raw s_barrier (T3/T4).
// kh stored PRE-SWIZZLED (e ^= (row&7)*8), vt PRE-SWIZZLED
// (us ^= ((e>>1)&3)*8) for attn's linear global_load_lds staging.
__global__ __launch_bounds__(512) void qkv_mfma(
    const float* __restrict__ theta, const float* __restrict__ pe_d,
    const unsigned short* __restrict__ whb,
    unsigned short* __restrict__ qh, unsigned short* __restrict__ ql,
    unsigned short* __restrict__ kh, unsigned short* __restrict__ vt)
{
    __shared__ __align__(16) unsigned short Ws[4][8192];   // 64KB W 4-buf

    int tid = threadIdx.x;
    int w = tid >> 6, lane = tid & 63;
    int quad = lane >> 4, l16 = lane & 15;
    int eh = w & 1;                     // e-half: frags eh*8..eh*8+7
    int xq = w >> 1;                    // x-quarter: rows xq*32..xq*32+31

    int b = blockIdx.x;                 // 0..767
    int xcd = b & 7, r = b >> 3;        // r 0..95
    int wsel = r % 3;
    int panel = (r / 3) * 8 + xcd;      // all 3 wsel of a panel share an XCD
    int rowBase = panel * 128;
    const unsigned short* wsrc = whb + (size_t)wsel * 65536;

    auto stageW = [&](int kt, int buf) {
        #pragma unroll
        for (int j = 0; j < 2; j++) {
            int g = w * 2 + j;          // wave-uniform chunk id, 0..15
            __builtin_amdgcn_global_load_lds(
                (GVC*)(wsrc + (size_t)g * 4096 + kt * 512 + lane * 8),
                (LDSV*)(Ws[buf] + g * 512), 16, 0, 0);
        }
    };

    // stages 0..2 issued first: in-flight under the X conversion below
    stageW(0, 0);
    stageW(1, 1);
    stageW(2, 2);

    // X quarter -> registers (hi/lo split), MFMA fragment layout:
    // xh[nx][kt] = rows xq*32+nx*16+l16, cols kt*32+quad*8..+7
    f4_t xh[2][8], xl[2][8];
    #pragma unroll
    for (int nx = 0; nx < 2; nx++) {
        int row = rowBase + xq * 32 + nx * 16 + l16;
        const float* tp = &theta[(size_t)row * D + quad * 8];
        const float* pp = &pe_d[(size_t)(row & (L - 1)) * D + quad * 8];
        #pragma unroll
        for (int kt = 0; kt < 8; kt++) {
            float4 t0 = reinterpret_cast<const float4*>(tp + kt * 32)[0];
            float4 t1 = reinterpret_cast<const float4*>(tp + kt * 32 + 4)[0];
            float4 p0 = reinterpret_cast<const float4*>(pp + kt * 32)[0];
            float4 p1 = reinterpret_cast<const float4*>(pp + kt * 32 + 4)[0];
            float xv[8] = {t0.x + p0.x, t0.y + p0.y, t0.z + p0.z, t0.w + p0.w,
                           t1.x + p1.x, t1.y + p1.y, t1.z + p1.z, t1.w + p1.w};
            union { unsigned short us[8]; f4_t f; } hu, lu;
            #pragma unroll
            for (int e = 0; e < 8; e++) {
                unsigned short hh = f2bf(xv[e]);
                hu.us[e] = hh;
                lu.us[e] = f2bf(xv[e] - bf2f(hh));
            }
            xh[nx][kt] = hu.f;
            xl[nx][kt] = lu.f;
        }
    }
    #pragma unroll
    for (int nx = 0; nx < 2; nx++)
        #pragma unroll
        for (int kt = 0; kt < 8; kt++) {
            asm volatile("" : "+v"(xh[nx][kt]));
            asm volatile("" : "+v"(xl[nx][kt]));
        }

    f4_t acc[16];
    #pragma unroll
    for (int i = 0; i < 16; i++) acc[i] = (f4_t){0.f, 0.f, 0.f, 0.f};

    #define FR(buf2d, g16) (*reinterpret_cast<const bf8_t*>(&(buf2d)[(g16) * 512 + quad * 128 + l16 * 8]))

    #pragma unroll
    for (int kt = 0; kt < 8; kt++) {
        int buf = kt & 3;
        // stage(kt) guaranteed done: allow stages kt+1,kt+2 (4 loads) in flight
        asm volatile("s_waitcnt vmcnt(4)" ::: "memory");
        __builtin_amdgcn_s_barrier();
        __builtin_amdgcn_sched_barrier(0);
        int nt = (kt + 3 < 8) ? kt + 3 : 7;        // clamp: uniform issue count
        stageW(nt, (kt + 3) & 3);

        if (wsel < 2) {
            #pragma unroll
            for (int ne = 0; ne < 8; ne++) {
                bf8_t aw = FR(Ws[buf], eh * 8 + ne);
                #pragma unroll
                for (int nx = 0; nx < 2; nx++) {
                    acc[ne * 2 + nx] = __builtin_amdgcn_mfma_f32_16x16x32_bf16(aw, __builtin_bit_cast(bf8_t, xh[nx][kt]), acc[ne * 2 + nx], 0, 0, 0);
                    acc[ne * 2 + nx] = __builtin_amdgcn_mfma_f32_16x16x32_bf16(aw, __builtin_bit_cast(bf8_t, xl[nx][kt]), acc[ne * 2 + nx], 0, 0, 0);
                }
            }
        } else {
            #pragma unroll
            for (int ne = 0; ne < 8; ne++) {
                bf8_t bw = FR(Ws[buf], eh * 8 + ne);
                #pragma unroll
                for (int mx = 0; mx < 2; mx++) {
                    acc[mx * 8 + ne] = __builtin_amdgcn_mfma_f32_16x16x32_bf16(__builtin_bit_cast(bf8_t, xh[mx][kt]), bw, acc[mx * 8 + ne], 0, 0, 0);
                    acc[mx * 8 + ne] = __builtin_amdgcn_mfma_f32_16x16x32_bf16(__builtin_bit_cast(bf8_t, xl[mx][kt]), bw, acc[mx * 8 + ne], 0, 0, 0);
                }
            }
        }
    }
    #undef FR

    // ---- epilogue (identical mapping to R8, which passed) ----
    if (wsel < 2) {
        float scale = (wsel == 0) ? 0.0625f : 1.0f;  // fold 1/sqrt(d) into q
        #pragma unroll
        for (int ne = 0; ne < 8; ne++) {
            #pragma unroll
            for (int nx = 0; nx < 2; nx++) {
                int e0 = eh * 128 + ne * 16 + quad * 4;
                size_t row = rowBase + xq * 32 + nx * 16 + l16;
                union { unsigned short us[4]; unsigned long long u; } ph, pl;
                #pragma unroll
                for (int rr = 0; rr < 4; rr++) {
                    float x = acc[ne * 2 + nx][rr] * scale;
                    unsigned short h = f2bf(x);
                    ph.us[rr] = h;
                    pl.us[rr] = f2bf(x - bf2f(h));
                }
                if (wsel == 0) {
                    *reinterpret_cast<unsigned long long*>(&qh[row * D + e0]) = ph.u;
                    *reinterpret_cast<unsigned long long*>(&ql[row * D + e0]) = pl.u;
                } else {
                    int e0s = e0 ^ ((l16 & 7) << 3);   // row&7 == l16&7
                    *reinterpret_cast<unsigned long long*>(&kh[row * D + e0s]) = ph.u;
                }
            }
        }
    } else {
        #pragma unroll
        for (int mx = 0; mx < 2; mx++) {
            #pragma unroll
            for (int ne = 0; ne < 8; ne++) {
                int row0 = rowBase + xq * 32 + mx * 16 + quad * 4;
                int e = eh * 128 + ne * 16 + l16;
                int head = row0 >> 10, kb = (row0 & 1023) >> 5, kk = row0 & 31;
                union { unsigned short us[4]; unsigned long long u; } pk;
                #pragma unroll
                for (int rr = 0; rr < 4; rr++) pk.us[rr] = f2bf(acc[mx * 8 + ne][rr]);
                int us_sw = (e * 32 + kk) ^ (((e >> 1) & 3) << 3);  // V-tile swizzle
                *reinterpret_cast<unsigned long long*>(
                    &vt[((size_t)(head * 32 + kb)) * 8192 + us_sw]) = pk.u;
            }
        }
    }
}

// ---------------- LDS-shared flash attention, 4-deep counted vmcnt ---------
// R8 diagnosis: per-iteration vmcnt(0) drain + __syncthreads at 1 block/CU
// exposed HBM latency (~5.2k cyc/iter vs ~1k work). v9: 4-deep K/V buffers,
// prefetch distance 3, s_waitcnt vmcnt(8) + raw s_barrier per iteration
// (T3/T4, m218: +38-73%). Stage count kept uniform by clamp-restaging the
// last tile into never-read buffers.
__device__ __forceinline__ void stage_tile(
    const unsigned short* kht, const unsigned short* vtt,
    unsigned short* Ks, unsigned short* Vs, int kt, int buf, int w, int lane)
{
    #pragma unroll
    for (int i = 0; i < 2; i++) {
        int ch = w * 2 + i;   // wave-uniform chunk id (LDS base must be uniform)
        __builtin_amdgcn_global_load_lds(
            (GVC*)(kht + (size_t)kt * 8192 + ch * 512 + lane * 8),
            (LDSV*)(Ks + buf * 8192 + ch * 512), 16, 0, 0);
        __builtin_amdgcn_global_load_lds(
            (GVC*)(vtt + (size_t)kt * 8192 + ch * 512 + lane * 8),
            (LDSV*)(Vs + buf * 8192 + ch * 512), 16, 0, 0);
    }
}

__global__ __launch_bounds__(512) void attn_v9(
    const unsigned short* __restrict__ qh, const unsigned short* __restrict__ ql,
    const unsigned short* __restrict__ kh, const unsigned short* __restrict__ vt,
    float* __restrict__ hout)
{
    __shared__ __align__(16) unsigned short Ks[4 * 8192];   // 64KB K 4-buf
    __shared__ __align__(16) unsigned short Vs[4 * 8192];   // 64KB V 4-buf
    __shared__ __align__(16) unsigned short Pb[8][16 * 40]; // 10KB P

    int tid = threadIdx.x;
    int w = tid >> 6, lane = tid & 63;
    int quad = lane >> 4, l16 = lane & 15;
    int b = blockIdx.x;
    int head = ((b & 7) << 2) + (b >> 6);     // 4 heads per XCD share L2
    int s = (b >> 3) & 7;
    int u = (w < 4) ? (4 * s + w) : (63 - 4 * s - (w - 4));  // mirrored units
    int Ts = 32 - 2 * s;                       // Ts >= 18 > 3
    int lim = u >> 1;
    size_t hb = (size_t)head * (L * D);
    const unsigned short* kht = kh + hb;
    const unsigned short* vtt = vt + (size_t)head * (32 * 8192);
    unsigned short* Pw = Pb[w];

    int q_g = u * 16 + l16;

    // Q fragments in registers; issued BEFORE stages so the first counted
    // vmcnt covers them too. asm keep-alive pins them.
    f4_t qfh[8], qfl[8];
    {
        const unsigned short* ph = qh + hb + (size_t)q_g * D + quad * 8;
        const unsigned short* pl = ql + hb + (size_t)q_g * D + quad * 8;
        #pragma unroll
        for (int c = 0; c < 8; c++) {
            qfh[c] = *reinterpret_cast<const f4_t*>(ph + c * 32);
            qfl[c] = *reinterpret_cast<const f4_t*>(pl + c * 32);
        }
    }
    #pragma unroll
    for (int c = 0; c < 8; c++) {
        asm volatile("" : "+v"(qfh[c]));
        asm volatile("" : "+v"(qfl[c]));
    }

    stage_tile(kht, vtt, Ks, Vs, 0, 0, w, lane);
    stage_tile(kht, vtt, Ks, Vs, 1, 1, w, lane);
    stage_tile(kht, vtt, Ks, Vs, 2, 2, w, lane);

    f4_t acc[16];
    #pragma unroll
    for (int i = 0; i < 16; i++) acc[i] = (f4_t){0.f, 0.f, 0.f, 0.f};
    float mrun = -1e30f, lrun = 0.f;

    int xm = (l16 & 7) << 3;                        // K e-swizzle (us)
    int vq = (quad * 8) ^ (((l16 >> 1) & 3) << 3);  // V swizzled col base

    #pragma unroll 1
    for (int kt = 0; kt < Ts; kt++) {
        // stage(kt) guaranteed done: allow stages kt+1,kt+2 (8 loads) in flight
        asm volatile("s_waitcnt vmcnt(8)" ::: "memory");
        __builtin_amdgcn_s_barrier();
        __builtin_amdgcn_sched_barrier(0);
        int nt = (kt + 3 < Ts) ? kt + 3 : Ts - 1;  // clamp: uniform issue count
        stage_tile(kht, vtt, Ks, Vs, nt, (kt + 3) & 3, w, lane);

        if (kt <= lim) {   // wave-uniform predicate
            const unsigned short* Kb = Ks + (kt & 3) * 8192;
            const unsigned short* Vb = Vs + (kt & 3) * 8192;
            int kBase = kt * 32;

            bf8_t kf0[8], kf1[8];
            #pragma unroll
            for (int c = 0; c < 8; c++) {
                int col = (quad * 8 + c * 32) ^ xm;
                kf0[c] = *reinterpret_cast<const bf8_t*>(&Kb[l16 * 256 + col]);
                kf1[c] = *reinterpret_cast<const bf8_t*>(&Kb[(16 + l16) * 256 + col]);
            }
            // V batch A: LDS-read latency hides under the QK MFMAs
            const unsigned short* vpb = Vb + l16 * 32 + vq;
            bf8_t vfA[8];
            #pragma unroll
            for (int dt = 0; dt < 8; dt++)
                vfA[dt] = *reinterpret_cast<const bf8_t*>(vpb + dt * 512);

            // dual accumulator chains: halves dependent-MFMA depth
            f4_t s0a = (f4_t){0.f,0.f,0.f,0.f}, s0b = (f4_t){0.f,0.f,0.f,0.f};
            f4_t s1a = (f4_t){0.f,0.f,0.f,0.f}, s1b = (f4_t){0.f,0.f,0.f,0.f};
            __builtin_amdgcn_s_setprio(1);
            #pragma unroll
            for (int c = 0; c < 8; c += 2) {
                s0a = __builtin_amdgcn_mfma_f32_16x16x32_bf16(kf0[c],     __builtin_bit_cast(bf8_t, qfh[c]),     s0a, 0, 0, 0);
                s0b = __builtin_amdgcn_mfma_f32_16x16x32_bf16(kf0[c + 1], __builtin_bit_cast(bf8_t, qfh[c + 1]), s0b, 0, 0, 0);
                s0a = __builtin_amdgcn_mfma_f32_16x16x32_bf16(kf0[c],     __builtin_bit_cast(bf8_t, qfl[c]),     s0a, 0, 0, 0);
                s0b = __builtin_amdgcn_mfma_f32_16x16x32_bf16(kf0[c + 1], __builtin_bit_cast(bf8_t, qfl[c + 1]), s0b, 0, 0, 0);
            }
            #pragma unroll
            for (int c = 0; c < 8; c += 2) {
                s1a = __builtin_amdgcn_mfma_f32_16x16x32_bf16(kf1[c],     __builtin_bit_cast(bf8_t, qfh[c]),     s1a, 0, 0, 0);
                s1b = __builtin_amdgcn_mfma_f32_16x16x32_bf16(kf1[c + 1], __builtin_bit_cast(bf8_t, qfh[c + 1]), s1b, 0, 0, 0);
                s1a = __builtin_amdgcn_mfma_f32_16x16x32_bf16(kf1[c],     __builtin_bit_cast(bf8_t, qfl[c]),     s1a, 0, 0, 0);
                s1b = __builtin_amdgcn_mfma_f32_16x16x32_bf16(kf1[c + 1], __builtin_bit_cast(bf8_t, qfl[c + 1]), s1b, 0, 0, 0);
            }
            __builtin_amdgcn_s_setprio(0);
            f4_t sc[2];
            sc[0] = s0a + s0b;
            sc[1] = s1a + s1b;

            // causal mask + per-lane softmax over 8 keys, quad-pair reduce
            float pv[2][4];
            float tm = -1e30f;
            #pragma unroll
            for (int t = 0; t < 2; t++)
                #pragma unroll
                for (int rr = 0; rr < 4; rr++) {
                    int key = kBase + t * 16 + quad * 4 + rr;
                    float sv = (key <= q_g) ? sc[t][rr] : -1e30f;
                    sc[t][rr] = sv;
                    tm = fmaxf(tm, sv);
                }
            tm = fmaxf(tm, __shfl_xor(tm, 16));
            tm = fmaxf(tm, __shfl_xor(tm, 32));
            bool grow = __any(tm > mrun);      // alpha==1 exactly if false
            float mnew = fmaxf(mrun, tm);
            float alpha = grow ? __expf(mrun - mnew) : 1.0f;
            mrun = mnew;
            float ts = 0.f;
            #pragma unroll
            for (int t = 0; t < 2; t++)
                #pragma unroll
                for (int rr = 0; rr < 4; rr++) {
                    float p = __expf(sc[t][rr] - mnew);
                    pv[t][rr] = p;
                    ts += p;
                }
            ts += __shfl_xor(ts, 16);
            ts += __shfl_xor(ts, 32);
            lrun = lrun * alpha + ts;

            // P write before O-rescale: LDS round-trip hides under the muls
            #pragma unroll
            for (int t = 0; t < 2; t++) {
                union { unsigned short us[4]; unsigned long long uu; } pk;
                #pragma unroll
                for (int rr = 0; rr < 4; rr++) pk.us[rr] = f2bf(pv[t][rr]);
                *reinterpret_cast<unsigned long long*>(&Pw[l16 * 40 + t * 16 + quad * 4]) = pk.uu;
            }
            // V batch B
            bf8_t vfB[8];
            #pragma unroll
            for (int dt = 0; dt < 8; dt++)
                vfB[dt] = *reinterpret_cast<const bf8_t*>(vpb + (8 + dt) * 512);
            if (grow) {
                #pragma unroll
                for (int dt = 0; dt < 16; dt++) acc[dt] *= alpha;
            }
            asm volatile("s_waitcnt lgkmcnt(0)" ::: "memory");
            bf8_t pf = *reinterpret_cast<const bf8_t*>(&Pw[l16 * 40 + quad * 8]);
            __builtin_amdgcn_s_setprio(1);
            #pragma unroll
            for (int dt = 0; dt < 8; dt++)
                acc[dt] = __builtin_amdgcn_mfma_f32_16x16x32_bf16(vfA[dt], pf, acc[dt], 0, 0, 0);
            #pragma unroll
            for (int dt = 0; dt < 8; dt++)
                acc[8 + dt] = __builtin_amdgcn_mfma_f32_16x16x32_bf16(vfB[dt], pf, acc[8 + dt], 0, 0, 0);
            __builtin_amdgcn_s_setprio(0);
        }
    }

    float inv = 1.f / lrun;
    float* dst = hout + hb + (size_t)q_g * D + quad * 4;
    #pragma unroll
    for (int dt = 0; dt < 16; dt++) {
        float4 o = {acc[dt][0] * inv, acc[dt][1] * inv,
                    acc[dt][2] * inv, acc[dt][3] * inv};
        *reinterpret_cast<float4*>(dst + dt * 16) = o;
    }
}

// ---------------- equivariant path: one wave per q row ---------------------
__global__ __launch_bounds__(256) void equiv_kernel(
    const float* __restrict__ xsb, float* __restrict__ xout)
{
    __shared__ float xs[L * NCH];
    int head = blockIdx.y;
    int tid = threadIdx.x;
    const float4* src = reinterpret_cast<const float4*>(xsb + (size_t)head * L * NCH);
    #pragma unroll
    for (int it = 0; it < 3; it++)
        reinterpret_cast<float4*>(xs)[tid + it * 256] = src[tid + it * 256];
    __syncthreads();

    int w = tid >> 6, lane = tid & 63;
    int q = blockIdx.x * 4 + w;
    float xq0 = xs[q * 3 + 0], xq1 = xs[q * 3 + 1], xq2 = xs[q * 3 + 2];

    float m = 0.f;
    for (int k = lane; k < q; k += 64) {
        float d0 = xq0 - xs[k * 3 + 0];
        float d1 = xq1 - xs[k * 3 + 1];
        float d2 = xq2 - xs[k * 3 + 2];
        m = fmaxf(m, d0 * d0 + d1 * d1 + d2 * d2);
    }
    #pragma unroll
    for (int off = 1; off < 64; off <<= 1) m = fmaxf(m, __shfl_xor(m, off));

    float s0 = 0.f, s1 = 0.f, s2 = 0.f, sn = 0.f;
    for (int k = lane; k < q; k += 64) {
        float d0 = xq0 - xs[k * 3 + 0];
        float d1 = xq1 - xs[k * 3 + 1];
        float d2 = xq2 - xs[k * 3 + 2];
        float wgt = __expf(d0 * d0 + d1 * d1 + d2 * d2 - m);
        sn += wgt;
        s0 += wgt * xs[k * 3 + 0];
        s1 += wgt * xs[k * 3 + 1];
        s2 += wgt * xs[k * 3 + 2];
    }
    #pragma unroll
    for (int off = 1; off < 64; off <<= 1) {
        sn += __shfl_xor(sn, off);
        s0 += __shfl_xor(s0, off);
        s1 += __shfl_xor(s1, off);
        s2 += __shfl_xor(s2, off);
    }
    float Z = sn + __expf(-m);
    float inv = 0.5f / Z;
    if (lane == 0) {
        size_t ob = (size_t)head * L * NCH + (size_t)q * NCH;
        xout[ob + 0] = xq0 + inv * (s0 - sn * xq0);
        xout[ob + 1] = xq1 + inv * (s1 - sn * xq1);
        xout[ob + 2] = xq2 + inv * (s2 - sn * xq2);
    }
}

extern "C" void kernel_launch(void* const* d_in, const int* in_sizes, int n_in,
                              void* d_out, int out_size, void* d_ws, size_t ws_size,
                              hipStream_t stream)
{
    (void)in_sizes; (void)n_in; (void)out_size; (void)ws_size;
    const float* theta = (const float*)d_in[0];
    const float* xi    = (const float*)d_in[1];
    const float* edge  = (const float*)d_in[2];
    const float* Wq    = (const float*)d_in[3];
    const float* Wk    = (const float*)d_in[4];
    const float* Wv    = (const float*)d_in[5];

    float* out  = (float*)d_out;
    float* hout = out;
    float* xout = out + 8388608;
    float* eout = out + 8388608 + 98304;

    const size_t NE = 8388608;
    unsigned short* base = (unsigned short*)d_ws;
    unsigned short* qh  = base;
    unsigned short* ql  = base + NE;
    unsigned short* kh  = base + 2 * NE;
    unsigned short* vt  = base + 3 * NE;
    unsigned short* whb = base + 4 * NE;                   // 196608 us
    float* pe_d = (float*)(base + 4 * NE + 196608);        // 1024*256 floats
    float* xsb  = pe_d + L * D;                            // 32*1024*3 floats

    prep_kernel<<<3296, 256, 0, stream>>>(edge, xi, Wq, Wk, Wv, pe_d, eout, xsb, whb);
    equiv_kernel<<<dim3(L / 4, HEADS), 256, 0, stream>>>(xsb, xout);
    qkv_mfma<<<768, 512, 0, stream>>>(theta, pe_d, whb, qh, ql, kh, vt);
    attn_v9<<<256, 512, 0, stream>>>(qh, ql, kh, vt, hout);
}

// Round 10
// 221.133 us; speedup vs baseline: 1.2362x; 1.2362x over previous
//
#include <hip/hip_runtime.h>
#include <math.h>

#define L    1024
#define D    256
#define NCH  3
#define HEADS 32      // B*N
#define EDIM 112
#define BATCH 4

typedef __bf16 bf8_t __attribute__((ext_vector_type(8)));
typedef float  f4_t  __attribute__((ext_vector_type(4)));

typedef __attribute__((address_space(1))) const void GVC;
typedef __attribute__((address_space(3))) void LDSV;

// RNE float->bf16
__device__ inline unsigned short f2bf(float x) {
    unsigned u = __float_as_uint(x);
    u += 0x7FFFu + ((u >> 16) & 1u);
    return (unsigned short)(u >> 16);
}
__device__ inline float bf2f(unsigned short h) {
    return __uint_as_float(((unsigned)h) << 16);
}

// ------- fused prologue: pe_d table + edge + xs + whb (frag-major bf16) ----
__global__ void prep_kernel(const float* __restrict__ edge, const float* __restrict__ xi,
                            const float* __restrict__ Wq, const float* __restrict__ Wk,
                            const float* __restrict__ Wv,
                            float* __restrict__ pe_d, float* __restrict__ eout,
                            float* __restrict__ xsb, unsigned short* __restrict__ whb)
{
    int idx = blockIdx.x * blockDim.x + threadIdx.x;
    if (idx < L * D) {
        int l = idx >> 8, i = idx & (D - 1);
        float expo = (float)(i & ~1) * (1.0f / (float)D);
        float ang = (float)l * __powf(10000.0f, -expo);
        pe_d[idx] = (i & 1) ? cosf(ang) : sinf(ang);
    } else if (idx < L * D + BATCH * L * EDIM) {
        int j = idx - L * D;
        int i = j % EDIM;
        int l = (j / EDIM) % L;
        float expo = (float)(i & ~1) * (1.0f / (float)EDIM);
        float ang = (float)l * __powf(10000.0f, -expo);
        eout[j] = edge[j] + ((i & 1) ? cosf(ang) : sinf(ang));
    } else if (idx < L * D + BATCH * L * EDIM + HEADS * L * NCH) {
        int j = idx - (L * D + BATCH * L * EDIM);
        int c = j % 3;
        int l = (j / 3) & (L - 1);
        float ang = (c == 2) ? (float)l * 0.0021544347f : (float)l;  // 10000^(-2/3)
        float pe = (c == 1) ? cosf(ang) : sinf(ang);
        xsb[j] = xi[j] + pe;
    } else {
        int j = idx - (L * D + BATCH * L * EDIM + HEADS * L * NCH);
        if (j < 3 * 8192) {                       // W -> bf16, fragment-major
            int wsel = j >> 13;
            int t = j & 8191;
            int g = t >> 9, u = (t >> 4) & 31, rr = t & 15;
            const float* W = (wsel == 0) ? Wq : (wsel == 1) ? Wk : Wv;
            const float4* s = reinterpret_cast<const float4*>(&W[(size_t)(g * 16 + rr) * D + u * 8]);
            float4 a = s[0], b = s[1];
            float x[8] = {a.x, a.y, a.z, a.w, b.x, b.y, b.z, b.w};
            union { unsigned short us[8]; float4 f4; } hv;
            #pragma unroll
            for (int q = 0; q < 8; q++) hv.us[q] = f2bf(x[q]);
            *reinterpret_cast<float4*>(&whb[(size_t)wsel * 65536 + g * 4096 + u * 128 + rr * 8]) = hv.f4;
        }
    }
}

// ---------------- QKV projection v8 (R8, best measured: 69.6us) ------------
// 512 threads (8 waves, wave = e-half x x-quarter), stageW + next-theta loads
// issued at the TOP of each iteration, conversion overlaps MFMA.
// kh stored PRE-SWIZZLED (e ^= (row&7)*8), vt PRE-SWIZZLED
// (us ^= ((e>>1)&3)*8) for attn's linear global_load_lds staging.
// R9 lesson: X-in-registers (256 forced regs) spills at the allocator's
// 128-VGPR occupancy target -> +64MB scratch traffic. Reverted.
__global__ __launch_bounds__(512) void qkv_mfma(
    const float* __restrict__ theta, const float* __restrict__ pe_d,
    const unsigned short* __restrict__ whb,
    unsigned short* __restrict__ qh, unsigned short* __restrict__ ql,
    unsigned short* __restrict__ kh, unsigned short* __restrict__ vt)
{
    __shared__ __align__(16) unsigned short XsH[2][4096];  // 16KB X-hi dbuf
    __shared__ __align__(16) unsigned short XsL[2][4096];  // 16KB X-lo dbuf
    __shared__ __align__(16) unsigned short Ws[2][8192];   // 32KB W dbuf

    int tid = threadIdx.x;
    int w = tid >> 6, lane = tid & 63;
    int quad = lane >> 4, l16 = lane & 15;
    int eh = w & 1;                     // e-half: frags eh*8..eh*8+7
    int xq = w >> 1;                    // x-quarter: frags xq*2, xq*2+1

    int b = blockIdx.x;                 // 0..767
    int xcd = b & 7, r = b >> 3;        // r 0..95
    int wsel = r % 3;
    int panel = (r / 3) * 8 + xcd;      // all 3 wsel of a panel share an XCD
    int rowBase = panel * 128;
    const unsigned short* wsrc = whb + (size_t)wsel * 65536;

    // conversion slot: thread -> (row sr, 8-elem k-unit) of the 128x32 X tile
    int sr = tid >> 2;                  // 0..127
    int ks8 = (tid & 3) * 8;            // 0,8,16,24
    int cg = sr >> 4, cr = sr & 15, cu = tid & 3;
    int xoff = cg * 512 + cu * 128 + cr * 8;     // fragment-major elem offset

    const float* tp_base = &theta[(size_t)(rowBase + sr) * D + ks8];
    const float* pp_base = &pe_d[(size_t)((rowBase + sr) & (L - 1)) * D + ks8];

    f4_t acc[16];
    #pragma unroll
    for (int i = 0; i < 16; i++) acc[i] = (f4_t){0.f, 0.f, 0.f, 0.f};

    auto stageW = [&](int kt, int buf) {
        #pragma unroll
        for (int j = 0; j < 2; j++) {
            int g = w * 2 + j;          // wave-uniform chunk id, 0..15
            __builtin_amdgcn_global_load_lds(
                (GVC*)(wsrc + (size_t)g * 4096 + kt * 512 + lane * 8),
                (LDSV*)(Ws[buf] + g * 512), 16, 0, 0);
        }
    };
    auto loadX = [&](int kt, float* xv) {
        const float* tp = tp_base + kt * 32;
        const float* pp = pp_base + kt * 32;
        float4 t0 = reinterpret_cast<const float4*>(tp)[0];
        float4 t1 = reinterpret_cast<const float4*>(tp)[1];
        float4 p0 = reinterpret_cast<const float4*>(pp)[0];
        float4 p1 = reinterpret_cast<const float4*>(pp)[1];
        xv[0] = t0.x + p0.x; xv[1] = t0.y + p0.y; xv[2] = t0.z + p0.z; xv[3] = t0.w + p0.w;
        xv[4] = t1.x + p1.x; xv[5] = t1.y + p1.y; xv[6] = t1.z + p1.z; xv[7] = t1.w + p1.w;
    };
    auto convX = [&](const float* xv, int buf) {
        union { unsigned short us[8]; float4 f4; } h, lo;
        #pragma unroll
        for (int e = 0; e < 8; e++) {
            unsigned short hh = f2bf(xv[e]);
            h.us[e] = hh;
            lo.us[e] = f2bf(xv[e] - bf2f(hh));
        }
        *reinterpret_cast<float4*>(&XsH[buf][xoff]) = h.f4;
        *reinterpret_cast<float4*>(&XsL[buf][xoff]) = lo.f4;
    };

    // prologue: tile 0
    {
        float xv[8];
        loadX(0, xv);
        convX(xv, 0);
        stageW(0, 0);
    }
    __syncthreads();

    #define FR(buf2d, g16) (*reinterpret_cast<const bf8_t*>(&(buf2d)[(g16) * 512 + quad * 128 + l16 * 8]))

    for (int kt = 0; kt < 8; kt++) {
        int buf = kt & 1;

        // next-tile staging issued FIRST: full MFMA phase covers the latency
        float xn[8];
        if (kt < 7) {
            stageW(kt + 1, buf ^ 1);
            loadX(kt + 1, xn);
        }
        __builtin_amdgcn_sched_barrier(0);

        bf8_t bxh[2], bxl[2];
        #pragma unroll
        for (int nx = 0; nx < 2; nx++) {
            bxh[nx] = FR(XsH[buf], xq * 2 + nx);
            bxl[nx] = FR(XsL[buf], xq * 2 + nx);
        }

        if (wsel < 2) {
            #pragma unroll
            for (int ne = 0; ne < 8; ne++) {
                bf8_t aw = FR(Ws[buf], eh * 8 + ne);
                #pragma unroll
                for (int nx = 0; nx < 2; nx++) {
                    acc[ne * 2 + nx] = __builtin_amdgcn_mfma_f32_16x16x32_bf16(aw, bxh[nx], acc[ne * 2 + nx], 0, 0, 0);
                    acc[ne * 2 + nx] = __builtin_amdgcn_mfma_f32_16x16x32_bf16(aw, bxl[nx], acc[ne * 2 + nx], 0, 0, 0);
                }
            }
        } else {
            #pragma unroll
            for (int ne = 0; ne < 8; ne++) {
                bf8_t bw = FR(Ws[buf], eh * 8 + ne);
                #pragma unroll
                for (int mx = 0; mx < 2; mx++) {
                    acc[mx * 8 + ne] = __builtin_amdgcn_mfma_f32_16x16x32_bf16(bxh[mx], bw, acc[mx * 8 + ne], 0, 0, 0);
                    acc[mx * 8 + ne] = __builtin_amdgcn_mfma_f32_16x16x32_bf16(bxl[mx], bw, acc[mx * 8 + ne], 0, 0, 0);
                }
            }
        }

        if (kt < 7) convX(xn, buf ^ 1);  // VALU; overlaps MFMA pipe tail
        __syncthreads();
    }
    #undef FR

    // ---- epilogue ----
    if (wsel < 2) {
        float scale = (wsel == 0) ? 0.0625f : 1.0f;  // fold 1/sqrt(d) into q
        #pragma unroll
        for (int ne = 0; ne < 8; ne++) {
            #pragma unroll
            for (int nx = 0; nx < 2; nx++) {
                int e0 = eh * 128 + ne * 16 + quad * 4;
                size_t row = rowBase + xq * 32 + nx * 16 + l16;
                union { unsigned short us[4]; unsigned long long u; } ph, pl;
                #pragma unroll
                for (int rr = 0; rr < 4; rr++) {
                    float x = acc[ne * 2 + nx][rr] * scale;
                    unsigned short h = f2bf(x);
                    ph.us[rr] = h;
                    pl.us[rr] = f2bf(x - bf2f(h));
                }
                if (wsel == 0) {
                    *reinterpret_cast<unsigned long long*>(&qh[row * D + e0]) = ph.u;
                    *reinterpret_cast<unsigned long long*>(&ql[row * D + e0]) = pl.u;
                } else {
                    int e0s = e0 ^ ((l16 & 7) << 3);   // row&7 == l16&7
                    *reinterpret_cast<unsigned long long*>(&kh[row * D + e0s]) = ph.u;
                }
            }
        }
    } else {
        #pragma unroll
        for (int mx = 0; mx < 2; mx++) {
            #pragma unroll
            for (int ne = 0; ne < 8; ne++) {
                int row0 = rowBase + xq * 32 + mx * 16 + quad * 4;
                int e = eh * 128 + ne * 16 + l16;
                int head = row0 >> 10, kb = (row0 & 1023) >> 5, kk = row0 & 31;
                union { unsigned short us[4]; unsigned long long u; } pk;
                #pragma unroll
                for (int rr = 0; rr < 4; rr++) pk.us[rr] = f2bf(acc[mx * 8 + ne][rr]);
                int us_sw = (e * 32 + kk) ^ (((e >> 1) & 3) << 3);  // V-tile swizzle
                *reinterpret_cast<unsigned long long*>(
                    &vt[((size_t)(head * 32 + kb)) * 8192 + us_sw]) = pk.u;
            }
        }
    }
}

// ---------------- flash attention v10: 2 k-tiles per barrier interval ------
// R8/R9 diagnosis: per-tile barrier at 1 block/CU leaves ONE active wave per
// SIMD whose serial chain (QK dep chain, 4 shfl_xor ~120cyc, exp, P LDS
// round-trip) is fully exposed (~5k cyc/iter vs ~1k work; MfmaUtil 14%).
// v10: super-tile = 2 k-tiles per interval. Tile B computed UNCONDITIONALLY
// under tile A's predicate — the causal mask zeroes out-of-range keys
// (exp(-1e30-m)=0, row-max via quad-reduce always has a real value) — so
// both tiles form one straight-line block the scheduler interleaves; barrier
// count halves (32->16); one merged softmax (one shuffle-reduce, one
// rescale) per 64 keys.
__device__ __forceinline__ void stage_super(
    const unsigned short* kht, const unsigned short* vtt,
    unsigned short* Ks, unsigned short* Vs, int st, int buf, int w, int lane)
{
    #pragma unroll
    for (int j = 0; j < 2; j++) {
        int t = st * 2 + j;
        #pragma unroll
        for (int i = 0; i < 2; i++) {
            int ch = w * 2 + i;   // wave-uniform chunk id (LDS base must be uniform)
            __builtin_amdgcn_global_load_lds(
                (GVC*)(kht + (size_t)t * 8192 + ch * 512 + lane * 8),
                (LDSV*)(Ks + buf * 16384 + j * 8192 + ch * 512), 16, 0, 0);
            __builtin_amdgcn_global_load_lds(
                (GVC*)(vtt + (size_t)t * 8192 + ch * 512 + lane * 8),
                (LDSV*)(Vs + buf * 16384 + j * 8192 + ch * 512), 16, 0, 0);
        }
    }
}

__global__ __launch_bounds__(512) __attribute__((amdgpu_waves_per_eu(2, 2)))
void attn_v10(
    const unsigned short* __restrict__ qh, const unsigned short* __restrict__ ql,
    const unsigned short* __restrict__ kh, const unsigned short* __restrict__ vt,
    float* __restrict__ hout)
{
    __shared__ __align__(16) unsigned short Ks[2 * 16384];     // 64KB K: 2 supers
    __shared__ __align__(16) unsigned short Vs[2 * 16384];     // 64KB V
    __shared__ __align__(16) unsigned short Pb[8][2][16 * 40]; // 20KB P (2 tiles)

    int tid = threadIdx.x;
    int w = tid >> 6, lane = tid & 63;
    int quad = lane >> 4, l16 = lane & 15;
    int b = blockIdx.x;
    int head = ((b & 7) << 2) + (b >> 6);     // 4 heads per XCD share L2
    int s = (b >> 3) & 7;
    int u = (w < 4) ? (4 * s + w) : (63 - 4 * s - (w - 4));  // mirrored units
    int Ts = 32 - 2 * s;                       // even
    int nSup = Ts >> 1;
    int limS = u >> 2;                         // supers this wave computes
    size_t hb = (size_t)head * (L * D);
    const unsigned short* kht = kh + hb;
    const unsigned short* vtt = vt + (size_t)head * (32 * 8192);
    unsigned short* PwA = Pb[w][0];
    unsigned short* PwB = Pb[w][1];

    int q_g = u * 16 + l16;

    // Q fragments in registers for the whole kernel
    f4_t qfh[8], qfl[8];
    {
        const unsigned short* ph = qh + hb + (size_t)q_g * D + quad * 8;
        const unsigned short* pl = ql + hb + (size_t)q_g * D + quad * 8;
        #pragma unroll
        for (int c = 0; c < 8; c++) {
            qfh[c] = *reinterpret_cast<const f4_t*>(ph + c * 32);
            qfl[c] = *reinterpret_cast<const f4_t*>(pl + c * 32);
        }
    }
    #pragma unroll
    for (int c = 0; c < 8; c++) {
        asm volatile("" : "+v"(qfh[c]));
        asm volatile("" : "+v"(qfl[c]));
    }

    stage_super(kht, vtt, Ks, Vs, 0, 0, w, lane);

    f4_t acc[16];
    #pragma unroll
    for (int i = 0; i < 16; i++) acc[i] = (f4_t){0.f, 0.f, 0.f, 0.f};
    float mrun = -1e30f, lrun = 0.f;

    int xm = (l16 & 7) << 3;                        // K e-swizzle (us)
    int vq = (quad * 8) ^ (((l16 >> 1) & 3) << 3);  // V swizzled col base

    #pragma unroll 1
    for (int st = 0; st < nSup; st++) {
        // drain own stage loads; barrier => whole super st resident
        asm volatile("s_waitcnt vmcnt(0)" ::: "memory");
        __builtin_amdgcn_s_barrier();
        __builtin_amdgcn_sched_barrier(0);
        int ns = (st + 1 < nSup) ? st + 1 : nSup - 1;  // clamp: uniform issue count
        stage_super(kht, vtt, Ks, Vs, ns, (st + 1) & 1, w, lane);

        if (st <= limS) {   // wave-uniform; tile B self-masks via causal mask
            const unsigned short* Kb0 = Ks + (st & 1) * 16384;
            const unsigned short* Vb0 = Vs + (st & 1) * 16384;
            const unsigned short* Kb1 = Kb0 + 8192;
            const unsigned short* Vb1 = Vb0 + 8192;
            int kBase = st * 64;

            // ---- QK tile A ----
            bf8_t kf0[8], kf1[8];
            #pragma unroll
            for (int c = 0; c < 8; c++) {
                int col = (quad * 8 + c * 32) ^ xm;
                kf0[c] = *reinterpret_cast<const bf8_t*>(&Kb0[l16 * 256 + col]);
                kf1[c] = *reinterpret_cast<const bf8_t*>(&Kb0[(16 + l16) * 256 + col]);
            }
            f4_t a0 = (f4_t){0.f,0.f,0.f,0.f}, a1 = (f4_t){0.f,0.f,0.f,0.f};
            f4_t a2 = (f4_t){0.f,0.f,0.f,0.f}, a3 = (f4_t){0.f,0.f,0.f,0.f};
            __builtin_amdgcn_s_setprio(1);
            #pragma unroll
            for (int c = 0; c < 8; c += 2) {
                a0 = __builtin_amdgcn_mfma_f32_16x16x32_bf16(kf0[c],     __builtin_bit_cast(bf8_t, qfh[c]),     a0, 0, 0, 0);
                a1 = __builtin_amdgcn_mfma_f32_16x16x32_bf16(kf0[c + 1], __builtin_bit_cast(bf8_t, qfh[c + 1]), a1, 0, 0, 0);
                a0 = __builtin_amdgcn_mfma_f32_16x16x32_bf16(kf0[c],     __builtin_bit_cast(bf8_t, qfl[c]),     a0, 0, 0, 0);
                a1 = __builtin_amdgcn_mfma_f32_16x16x32_bf16(kf0[c + 1], __builtin_bit_cast(bf8_t, qfl[c + 1]), a1, 0, 0, 0);
                a2 = __builtin_amdgcn_mfma_f32_16x16x32_bf16(kf1[c],     __builtin_bit_cast(bf8_t, qfh[c]),     a2, 0, 0, 0);
                a3 = __builtin_amdgcn_mfma_f32_16x16x32_bf16(kf1[c + 1], __builtin_bit_cast(bf8_t, qfh[c + 1]), a3, 0, 0, 0);
                a2 = __builtin_amdgcn_mfma_f32_16x16x32_bf16(kf1[c],     __builtin_bit_cast(bf8_t, qfl[c]),     a2, 0, 0, 0);
                a3 = __builtin_amdgcn_mfma_f32_16x16x32_bf16(kf1[c + 1], __builtin_bit_cast(bf8_t, qfl[c + 1]), a3, 0, 0, 0);
            }
            __builtin_amdgcn_s_setprio(0);
            f4_t scA[2];
            scA[0] = a0 + a1;
            scA[1] = a2 + a3;

            // ---- QK tile B (registers of kf0/kf1 recycled) ----
            bf8_t kf2[8], kf3[8];
            #pragma unroll
            for (int c = 0; c < 8; c++) {
                int col = (quad * 8 + c * 32) ^ xm;
                kf2[c] = *reinterpret_cast<const bf8_t*>(&Kb1[l16 * 256 + col]);
                kf3[c] = *reinterpret_cast<const bf8_t*>(&Kb1[(16 + l16) * 256 + col]);
            }
            f4_t b0 = (f4_t){0.f,0.f,0.f,0.f}, b1 = (f4_t){0.f,0.f,0.f,0.f};
            f4_t b2 = (f4_t){0.f,0.f,0.f,0.f}, b3 = (f4_t){0.f,0.f,0.f,0.f};
            __builtin_amdgcn_s_setprio(1);
            #pragma unroll
            for (int c = 0; c < 8; c += 2) {
                b0 = __builtin_amdgcn_mfma_f32_16x16x32_bf16(kf2[c],     __builtin_bit_cast(bf8_t, qfh[c]),     b0, 0, 0, 0);
                b1 = __builtin_amdgcn_mfma_f32_16x16x32_bf16(kf2[c + 1], __builtin_bit_cast(bf8_t, qfh[c + 1]), b1, 0, 0, 0);
                b0 = __builtin_amdgcn_mfma_f32_16x16x32_bf16(kf2[c],     __builtin_bit_cast(bf8_t, qfl[c]),     b0, 0, 0, 0);
                b1 = __builtin_amdgcn_mfma_f32_16x16x32_bf16(kf2[c + 1], __builtin_bit_cast(bf8_t, qfl[c + 1]), b1, 0, 0, 0);
                b2 = __builtin_amdgcn_mfma_f32_16x16x32_bf16(kf3[c],     __builtin_bit_cast(bf8_t, qfh[c]),     b2, 0, 0, 0);
                b3 = __builtin_amdgcn_mfma_f32_16x16x32_bf16(kf3[c + 1], __builtin_bit_cast(bf8_t, qfh[c + 1]), b3, 0, 0, 0);
                b2 = __builtin_amdgcn_mfma_f32_16x16x32_bf16(kf3[c],     __builtin_bit_cast(bf8_t, qfl[c]),     b2, 0, 0, 0);
                b3 = __builtin_amdgcn_mfma_f32_16x16x32_bf16(kf3[c + 1], __builtin_bit_cast(bf8_t, qfl[c + 1]), b3, 0, 0, 0);
            }
            __builtin_amdgcn_s_setprio(0);
            f4_t scB[2];
            scB[0] = b0 + b1;
            scB[1] = b2 + b3;

            // V tile A batch 0 issued early: hides under softmax
            const unsigned short* vp0 = Vb0 + l16 * 32 + vq;
            const unsigned short* vp1 = Vb1 + l16 * 32 + vq;
            bf8_t vfA[8];
            #pragma unroll
            for (int dt = 0; dt < 8; dt++)
                vfA[dt] = *reinterpret_cast<const bf8_t*>(vp0 + dt * 512);

            // ---- merged softmax over 64 keys (both tiles) ----
            float pvA[2][4], pvB[2][4];
            float tm = -1e30f;
            #pragma unroll
            for (int t = 0; t < 2; t++)
                #pragma unroll
                for (int rr = 0; rr < 4; rr++) {
                    int keyA = kBase + t * 16 + quad * 4 + rr;
                    int keyB = keyA + 32;
                    float svA = (keyA <= q_g) ? scA[t][rr] : -1e30f;
                    float svB = (keyB <= q_g) ? scB[t][rr] : -1e30f;
                    scA[t][rr] = svA;
                    scB[t][rr] = svB;
                    tm = fmaxf(tm, fmaxf(svA, svB));
                }
            tm = fmaxf(tm, __shfl_xor(tm, 16));
            tm = fmaxf(tm, __shfl_xor(tm, 32));
            bool grow = __any(tm > mrun);      // alpha==1 exactly if false
            float mnew = fmaxf(mrun, tm);
            float alpha = grow ? __expf(mrun - mnew) : 1.0f;
            mrun = mnew;
            float ts = 0.f;
            #pragma unroll
            for (int t = 0; t < 2; t++)
                #pragma unroll
                for (int rr = 0; rr < 4; rr++) {
                    float pA = __expf(scA[t][rr] - mnew);
                    float pB = __expf(scB[t][rr] - mnew);
                    pvA[t][rr] = pA;
                    pvB[t][rr] = pB;
                    ts += pA + pB;
                }
            ts += __shfl_xor(ts, 16);
            ts += __shfl_xor(ts, 32);
            lrun = lrun * alpha + ts;

            // P writes (both tiles) before the O-rescale
            #pragma unroll
            for (int t = 0; t < 2; t++) {
                union { unsigned short us[4]; unsigned long long uu; } pkA, pkB;
                #pragma unroll
                for (int rr = 0; rr < 4; rr++) {
                    pkA.us[rr] = f2bf(pvA[t][rr]);
                    pkB.us[rr] = f2bf(pvB[t][rr]);
                }
                *reinterpret_cast<unsigned long long*>(&PwA[l16 * 40 + t * 16 + quad * 4]) = pkA.uu;
                *reinterpret_cast<unsigned long long*>(&PwB[l16 * 40 + t * 16 + quad * 4]) = pkB.uu;
            }
            if (grow) {
                #pragma unroll
                for (int dt = 0; dt < 16; dt++) acc[dt] *= alpha;
            }
            asm volatile("s_waitcnt lgkmcnt(0)" ::: "memory");
            bf8_t pfA = *reinterpret_cast<const bf8_t*>(&PwA[l16 * 40 + quad * 8]);
            __builtin_amdgcn_s_setprio(1);
            #pragma unroll
            for (int dt = 0; dt < 8; dt++)
                acc[dt] = __builtin_amdgcn_mfma_f32_16x16x32_bf16(vfA[dt], pfA, acc[dt], 0, 0, 0);
            __builtin_amdgcn_s_setprio(0);
            bf8_t vfA2[8];
            #pragma unroll
            for (int dt = 0; dt < 8; dt++)
                vfA2[dt] = *reinterpret_cast<const bf8_t*>(vp0 + (8 + dt) * 512);
            __builtin_amdgcn_s_setprio(1);
            #pragma unroll
            for (int dt = 0; dt < 8; dt++)
                acc[8 + dt] = __builtin_amdgcn_mfma_f32_16x16x32_bf16(vfA2[dt], pfA, acc[8 + dt], 0, 0, 0);
            __builtin_amdgcn_s_setprio(0);
            // tile B PV
            bf8_t vfB[8];
            #pragma unroll
            for (int dt = 0; dt < 8; dt++)
                vfB[dt] = *reinterpret_cast<const bf8_t*>(vp1 + dt * 512);
            bf8_t pfB = *reinterpret_cast<const bf8_t*>(&PwB[l16 * 40 + quad * 8]);
            __builtin_amdgcn_s_setprio(1);
            #pragma unroll
            for (int dt = 0; dt < 8; dt++)
                acc[dt] = __builtin_amdgcn_mfma_f32_16x16x32_bf16(vfB[dt], pfB, acc[dt], 0, 0, 0);
            __builtin_amdgcn_s_setprio(0);
            bf8_t vfB2[8];
            #pragma unroll
            for (int dt = 0; dt < 8; dt++)
                vfB2[dt] = *reinterpret_cast<const bf8_t*>(vp1 + (8 + dt) * 512);
            __builtin_amdgcn_s_setprio(1);
            #pragma unroll
            for (int dt = 0; dt < 8; dt++)
                acc[8 + dt] = __builtin_amdgcn_mfma_f32_16x16x32_bf16(vfB2[dt], pfB, acc[8 + dt], 0, 0, 0);
            __builtin_amdgcn_s_setprio(0);
        }
    }

    float inv = 1.f / lrun;
    float* dst = hout + hb + (size_t)q_g * D + quad * 4;
    #pragma unroll
    for (int dt = 0; dt < 16; dt++) {
        float4 o = {acc[dt][0] * inv, acc[dt][1] * inv,
                    acc[dt][2] * inv, acc[dt][3] * inv};
        *reinterpret_cast<float4*>(dst + dt * 16) = o;
    }
}

// ---------------- equivariant path: one wave per q row ---------------------
__global__ __launch_bounds__(256) void equiv_kernel(
    const float* __restrict__ xsb, float* __restrict__ xout)
{
    __shared__ float xs[L * NCH];
    int head = blockIdx.y;
    int tid = threadIdx.x;
    const float4* src = reinterpret_cast<const float4*>(xsb + (size_t)head * L * NCH);
    #pragma unroll
    for (int it = 0; it < 3; it++)
        reinterpret_cast<float4*>(xs)[tid + it * 256] = src[tid + it * 256];
    __syncthreads();

    int w = tid >> 6, lane = tid & 63;
    int q = blockIdx.x * 4 + w;
    float xq0 = xs[q * 3 + 0], xq1 = xs[q * 3 + 1], xq2 = xs[q * 3 + 2];

    float m = 0.f;
    for (int k = lane; k < q; k += 64) {
        float d0 = xq0 - xs[k * 3 + 0];
        float d1 = xq1 - xs[k * 3 + 1];
        float d2 = xq2 - xs[k * 3 + 2];
        m = fmaxf(m, d0 * d0 + d1 * d1 + d2 * d2);
    }
    #pragma unroll
    for (int off = 1; off < 64; off <<= 1) m = fmaxf(m, __shfl_xor(m, off));

    float s0 = 0.f, s1 = 0.f, s2 = 0.f, sn = 0.f;
    for (int k = lane; k < q; k += 64) {
        float d0 = xq0 - xs[k * 3 + 0];
        float d1 = xq1 - xs[k * 3 + 1];
        float d2 = xq2 - xs[k * 3 + 2];
        float wgt = __expf(d0 * d0 + d1 * d1 + d2 * d2 - m);
        sn += wgt;
        s0 += wgt * xs[k * 3 + 0];
        s1 += wgt * xs[k * 3 + 1];
        s2 += wgt * xs[k * 3 + 2];
    }
    #pragma unroll
    for (int off = 1; off < 64; off <<= 1) {
        sn += __shfl_xor(sn, off);
        s0 += __shfl_xor(s0, off);
        s1 += __shfl_xor(s1, off);
        s2 += __shfl_xor(s2, off);
    }
    float Z = sn + __expf(-m);
    float inv = 0.5f / Z;
    if (lane == 0) {
        size_t ob = (size_t)head * L * NCH + (size_t)q * NCH;
        xout[ob + 0] = xq0 + inv * (s0 - sn * xq0);
        xout[ob + 1] = xq1 + inv * (s1 - sn * xq1);
        xout[ob + 2] = xq2 + inv * (s2 - sn * xq2);
    }
}

extern "C" void kernel_launch(void* const* d_in, const int* in_sizes, int n_in,
                              void* d_out, int out_size, void* d_ws, size_t ws_size,
                              hipStream_t stream)
{
    (void)in_sizes; (void)n_in; (void)out_size; (void)ws_size;
    const float* theta = (const float*)d_in[0];
    const float* xi    = (const float*)d_in[1];
    const float* edge  = (const float*)d_in[2];
    const float* Wq    = (const float*)d_in[3];
    const float* Wk    = (const float*)d_in[4];
    const float* Wv    = (const float*)d_in[5];

    float* out  = (float*)d_out;
    float* hout = out;
    float* xout = out + 8388608;
    float* eout = out + 8388608 + 98304;

    const size_t NE = 8388608;
    unsigned short* base = (unsigned short*)d_ws;
    unsigned short* qh  = base;
    unsigned short* ql  = base + NE;
    unsigned short* kh  = base + 2 * NE;
    unsigned short* vt  = base + 3 * NE;
    unsigned short* whb = base + 4 * NE;                   // 196608 us
    float* pe_d = (float*)(base + 4 * NE + 196608);        // 1024*256 floats
    float* xsb  = pe_d + L * D;                            // 32*1024*3 floats

    prep_kernel<<<3296, 256, 0, stream>>>(edge, xi, Wq, Wk, Wv, pe_d, eout, xsb, whb);
    equiv_kernel<<<dim3(L / 4, HEADS), 256, 0, stream>>>(xsb, xout);
    qkv_mfma<<<768, 512, 0, stream>>>(theta, pe_d, whb, qh, ql, kh, vt);
    attn_v10<<<256, 512, 0, stream>>>(qh, ql, kh, vt, hout);
}